// Round 18
// baseline (5103.449 us; speedup 1.0000x reference)
//
#include <hip/hip_runtime.h>
#include <hip/hip_bf16.h>
#include <cstdint>
#include <cstddef>

#define NN 20000
#define HH 128
#define MM 16
#define KK 4000
#define EE 400000

typedef __attribute__((ext_vector_type(16))) float f16v;
typedef __attribute__((ext_vector_type(8))) short short8;   // MFMA A/B operand
typedef __attribute__((ext_vector_type(4))) float f32x4;    // MFMA accumulator
typedef __attribute__((ext_vector_type(8), may_alias)) short s8ma;
typedef __attribute__((ext_vector_type(4), may_alias)) float f4ma;

__device__ __forceinline__ float gelu_f(float x) {
  return 0.5f * x * (1.0f + erff(x * 0.70710678118654752440f));
}

__device__ __forceinline__ unsigned short f2bf(float f) {
  union { float f; unsigned u; } v; v.f = f;
  unsigned u = v.u;
  unsigned r = (u + 0x7FFFu + ((u >> 16) & 1u)) >> 16;  // RNE
  return (unsigned short)r;
}
__device__ __forceinline__ float bf2f(unsigned short s) {
  union { unsigned u; float f; } v; v.u = ((unsigned)s) << 16; return v.f;
}

// ---------------- GCN helper kernels ----------------

__global__ void zero1_kernel(int* __restrict__ a, int n) {
  int i = blockIdx.x * 256 + threadIdx.x;
  if (i < n) a[i] = 0;
}

__global__ void count7_kernel(const int* __restrict__ edges, int* __restrict__ cnt7, int n7) {
  int e = blockIdx.x * 256 + threadIdx.x;
  if (e < n7) {
    int t = e / EE, i = e - t * EE;
    int d = edges[(size_t)t * 2 * EE + EE + i];
    atomicAdd(&cnt7[t * NN + d], 1);
  }
}

__global__ void dinv_kernel(const int* __restrict__ cnt, float* __restrict__ dinv, int n) {
  int i = blockIdx.x * 256 + threadIdx.x;
  if (i < n) dinv[i] = rsqrtf((float)(cnt[i] + 1));
}

__global__ void scan7_kernel(const int* __restrict__ cnt7, int* __restrict__ offs7) {
  __shared__ int sh[1024];
  __shared__ int carry_s;
  const int b = blockIdx.x;
  const int* cnt = cnt7 + b * NN;
  int* offs = offs7 + b * (NN + 1);
  int tid = threadIdx.x;
  if (tid == 0) carry_s = 0;
  __syncthreads();
  for (int base = 0; base < NN; base += 1024) {
    int i = base + tid;
    int v = (i < NN) ? cnt[i] : 0;
    sh[tid] = v;
    __syncthreads();
    for (int off = 1; off < 1024; off <<= 1) {
      int t = (tid >= off) ? sh[tid - off] : 0;
      __syncthreads();
      sh[tid] += t;
      __syncthreads();
    }
    int carry = carry_s;
    if (i < NN) offs[i] = carry + sh[tid] - v;
    __syncthreads();
    if (tid == 1023) carry_s = carry + sh[1023];
    __syncthreads();
  }
  if (tid == 0) offs[NN] = carry_s;
}

__global__ void fillcsr_kernel(const int* __restrict__ esrc, const int* __restrict__ edst,
                               const int* __restrict__ offs, int* __restrict__ cursor,
                               const float* __restrict__ dinv,
                               int* __restrict__ csrc, float* __restrict__ cnorm, int n) {
  int e = blockIdx.x * 256 + threadIdx.x;
  if (e < n) {
    int s = esrc[e], d = edst[e];
    int pos = offs[d] + atomicAdd(&cursor[d], 1);
    csrc[pos] = s;
    cnorm[pos] = dinv[s] * dinv[d];
  }
}

__global__ __launch_bounds__(128) void agg_kernel(const float* __restrict__ X,
    const int* __restrict__ csrc, const float* __restrict__ cnorm,
    const int* __restrict__ offs, const float* __restrict__ dinv,
    const float* __restrict__ bias, int relu, float* __restrict__ Y) {
  int i = blockIdx.x, c = threadIdx.x;
  float di = dinv[i];
  float acc = X[(size_t)i * HH + c] * di * di;
  int s = offs[i], e = offs[i + 1];
  for (int j = s; j < e; ++j) {
    acc += X[(size_t)csrc[j] * HH + c] * cnorm[j];
  }
  acc += bias[c];
  if (relu) acc = fmaxf(acc, 0.f);
  Y[(size_t)i * HH + c] = acc;
}

__global__ __launch_bounds__(128) void gemm128_kernel(const float* __restrict__ X,
    const float* __restrict__ W, float* __restrict__ Y, int nrows) {
  __shared__ float Ws[128 * 129];
  __shared__ float Xs[8 * 128];
  int tid = threadIdx.x;
  for (int idx = tid; idx < 16384; idx += 128) {
    int o = idx >> 7, k = idx & 127;
    Ws[o * 129 + k] = W[idx];
  }
  __syncthreads();
  for (int row0 = blockIdx.x * 8; row0 < nrows; row0 += gridDim.x * 8) {
    int nr = min(8, nrows - row0);
    for (int idx = tid; idx < nr * 128; idx += 128) Xs[idx] = X[(size_t)row0 * 128 + idx];
    __syncthreads();
    float acc[8] = {0, 0, 0, 0, 0, 0, 0, 0};
    for (int k = 0; k < 128; ++k) {
      float w = Ws[tid * 129 + k];
#pragma unroll
      for (int r = 0; r < 8; ++r) acc[r] += w * Xs[r * 128 + k];
    }
    for (int r = 0; r < nr; ++r) Y[(size_t)(row0 + r) * 128 + tid] = acc[r];
    __syncthreads();
  }
}

__global__ void mask_kernel(const int* __restrict__ nodes, float* __restrict__ H, int kn) {
  int idx = blockIdx.x * 256 + threadIdx.x;
  if (idx < kn * HH) {
    int j = idx >> 7, c = idx & 127;
    H[(size_t)nodes[j] * HH + c] = 0.f;
  }
}

__global__ void bcast_kernel(float* __restrict__ out, int total) {
  int idx = blockIdx.x * 256 + threadIdx.x + 128;
  if (idx < total) out[idx] = out[idx & 127];
}

// Pre-convert channel weights to bf16 (row-major), once.
__global__ void wprep_kernel(const float* __restrict__ w1, const float* __restrict__ w2,
                             unsigned short* __restrict__ b1, unsigned short* __restrict__ b2) {
  int i = blockIdx.x * 256 + threadIdx.x;
  if (i < 16384) { b1[i] = f2bf(w1[i]); b2[i] = f2bf(w2[i]); }
}

// ---------------- mixer v18: v16 on a 128-reg diet -> 2 blocks/CU ----------------
// Identical math/layout to validated v16 (bf16 hi/lo tiles pitch 136, W bf16).
// Changes: (a) W fragments loaded TRANSIENTLY inside P4/P5 from pre-converted
// bf16 arrays (kills the 64 persistent VGPRs); (b) __launch_bounds__(256,2)
// accepts the 128-reg cap, which now fits spill-free -> 2 blocks/CU resident
// (LDS 74.5KB x2 = 149KB <= 160KB).

__global__ __launch_bounds__(256, 2) void mixer18_kernel(
    const float* __restrict__ hbufs,  // [7][NN][HH]
    const unsigned short* __restrict__ wbf1, const unsigned short* __restrict__ wbf2,
    const float* __restrict__ tn_g, const float* __restrict__ tn_b,
    const float* __restrict__ tok_w1, const float* __restrict__ tok_b1,
    const float* __restrict__ tok_w2, const float* __restrict__ tok_b2,
    const float* __restrict__ cn_g, const float* __restrict__ cn_b,
    const float* __restrict__ ch_b1, const float* __restrict__ ch_b2,
    float* __restrict__ out, int total_items, int niter) {
  __shared__ __align__(16) float zw[64 * 132];           // 33.8 KB f32 x tile
  __shared__ __align__(16) unsigned short zh[64 * 136];  // 17.4 KB bf16 hi
  __shared__ __align__(16) unsigned short zl[64 * 136];  // 17.4 KB bf16 lo
  __shared__ float fout[4 * 128];
  __shared__ float tg[128], tbv[128], cg[128], cbv[128], cb1v[128], cb2v[128];
  __shared__ float tw1s[256], tw2s[256], tb1s[16], tb2s[16];

  const int tid = threadIdx.x;
  const int lane = tid & 63;
  const int wv = tid >> 6;        // wave 0..3 -> og pair {2wv, 2wv+1}
  const int q = lane >> 4;
  const int h = lane & 15;

  if (tid < 128) {
    tg[tid] = tn_g[tid]; tbv[tid] = tn_b[tid];
    cg[tid] = cn_g[tid]; cbv[tid] = cn_b[tid];
    cb1v[tid] = ch_b1[tid]; cb2v[tid] = ch_b2[tid];
  }
  tw1s[tid] = tok_w1[tid];
  tw2s[tid] = tok_w2[tid];
  if (tid < 16) { tb1s[tid] = tok_b1[tid]; tb2s[tid] = tok_b2[tid]; }
  __syncthreads();

  // per-lane W-fragment base offsets (shorts): row o = (2wv+j)*16+h, col k0
  const int wbase0 = ((2 * wv) * 16 + h) * 128 + q * 8;
  const int wbase1 = ((2 * wv + 1) * 16 + h) * 128 + q * 8;

  // P1/P3: row lr (0..63), 4 threads/row, 32 ch each.
  const int lr = tid >> 2;
  const int lq = tid & 3;
  // P2: col c2 of nodes n0 and n0+2.
  const int c2 = tid & 127;
  const int n0 = tid >> 7;

  for (int it = 0; it < niter; ++it) {
    const int item4 = it * gridDim.x + blockIdx.x;

    // ---- P1: load 4 nodes, LN1 stats per row -> zw (x + mu,rs) ----
    {
      const int n = lr >> 4, tok = lr & 15;
      const int item = item4 * 4 + n;
      const bool act = item < total_items;
      int t = 0, node = 0;
      if (act && item < 7 * NN) { t = item / NN + 1; node = item % NN; }
      int src_t = tok - (MM - t);
      f4ma x[8];
      if (act && src_t >= 0) {
        const float* hp = hbufs + ((size_t)src_t * NN + node) * HH + lq * 32;
#pragma unroll
        for (int j = 0; j < 8; ++j) x[j] = *(const f4ma*)(hp + 4 * j);
      } else {
#pragma unroll
        for (int j = 0; j < 8; ++j) x[j] = (f4ma){0.f, 0.f, 0.f, 0.f};
      }
      float s = 0.f, ss = 0.f;
#pragma unroll
      for (int j = 0; j < 8; ++j) {
        s += x[j].x + x[j].y + x[j].z + x[j].w;
        ss += x[j].x * x[j].x + x[j].y * x[j].y + x[j].z * x[j].z + x[j].w * x[j].w;
      }
      s += __shfl_xor(s, 1); ss += __shfl_xor(ss, 1);
      s += __shfl_xor(s, 2); ss += __shfl_xor(ss, 2);
      float mu = s * (1.f / 128.f);
      float var = fmaxf(ss * (1.f / 128.f) - mu * mu, 0.f);
      float rs = rsqrtf(var + 1e-5f);
#pragma unroll
      for (int j = 0; j < 8; ++j) *(f4ma*)&zw[lr * 132 + lq * 32 + 4 * j] = x[j];
      if (lq == 0) { zw[lr * 132 + 128] = mu; zw[lr * 132 + 129] = rs; }
    }
    __syncthreads();   // (1)

    // ---- P2: token-MLP, all 256 threads, cols c2 of nodes n0, n0+2 ----
    {
      const int rb0 = n0 * 16 * 132, rb1 = (n0 + 2) * 16 * 132;
      const float tgc = tg[c2], tbc = tbv[c2];
      f16v a0v, a1v;
#pragma unroll
      for (int hd = 0; hd < 16; ++hd) { float b = tb1s[hd]; a0v[hd] = b; a1v[hd] = b; }
#pragma unroll
      for (int r = 0; r < 16; ++r) {
        float x0 = zw[rb0 + r * 132 + c2];
        float m0 = zw[rb0 + r * 132 + 128], q0 = zw[rb0 + r * 132 + 129];
        float x1 = zw[rb1 + r * 132 + c2];
        float m1 = zw[rb1 + r * 132 + 128], q1 = zw[rb1 + r * 132 + 129];
        float z0 = (x0 - m0) * q0 * tgc + tbc;
        float z1 = (x1 - m1) * q1 * tgc + tbc;
#pragma unroll
        for (int hd = 0; hd < 16; ++hd) {
          float w = tw1s[hd * 16 + r];
          a0v[hd] += w * z0; a1v[hd] += w * z1;
        }
      }
#pragma unroll
      for (int hd = 0; hd < 16; ++hd) { a0v[hd] = gelu_f(a0v[hd]); a1v[hd] = gelu_f(a1v[hd]); }
      float cs0 = 0.f, cs1 = 0.f;
#pragma unroll
      for (int r = 0; r < 16; ++r) {
        float o0 = tb2s[r], o1 = tb2s[r];
#pragma unroll
        for (int hd = 0; hd < 16; ++hd) {
          float w = tw2s[r * 16 + hd];
          o0 += w * a0v[hd]; o1 += w * a1v[hd];
        }
        float nx0 = zw[rb0 + r * 132 + c2] + o0;
        float nx1 = zw[rb1 + r * 132 + c2] + o1;
        cs0 += nx0; cs1 += nx1;
        zw[rb0 + r * 132 + c2] = nx0;
        zw[rb1 + r * 132 + c2] = nx1;
      }
      fout[n0 * 128 + c2] = cs0;
      fout[(n0 + 2) * 128 + c2] = cs1;
    }
    __syncthreads();   // (2)

    // ---- P3: LN2 per row -> z2 as bf16 hi/lo (pitch 136) ----
    {
      f4ma x[8];
#pragma unroll
      for (int j = 0; j < 8; ++j) x[j] = *(const f4ma*)&zw[lr * 132 + lq * 32 + 4 * j];
      float s = 0.f, ss = 0.f;
#pragma unroll
      for (int j = 0; j < 8; ++j) {
        s += x[j].x + x[j].y + x[j].z + x[j].w;
        ss += x[j].x * x[j].x + x[j].y * x[j].y + x[j].z * x[j].z + x[j].w * x[j].w;
      }
      s += __shfl_xor(s, 1); ss += __shfl_xor(ss, 1);
      s += __shfl_xor(s, 2); ss += __shfl_xor(ss, 2);
      float mu = s * (1.f / 128.f);
      float var = fmaxf(ss * (1.f / 128.f) - mu * mu, 0.f);
      float rs = rsqrtf(var + 1e-5f);
#pragma unroll
      for (int j = 0; j < 4; ++j) {
        int c0 = lq * 32 + 8 * j;
        short8 ph, pl;
#pragma unroll
        for (int e = 0; e < 8; ++e) {
          int c = c0 + e;
          float xe = (e < 4) ? ((const float*)&x[2 * j])[e] : ((const float*)&x[2 * j + 1])[e - 4];
          float zf = (xe - mu) * rs * cg[c] + cbv[c];
          unsigned short hi = f2bf(zf);
          ph[e] = (short)hi;
          pl[e] = (short)f2bf(zf - bf2f(hi));
        }
        *(s8ma*)&zh[lr * 136 + c0] = (s8ma)ph;
        *(s8ma*)&zl[lr * 136 + c0] = (s8ma)pl;
      }
    }
    __syncthreads();   // (3)

    // ---- P4: MFMA matmul1 (transient W frags) -> hidden bf16 hi/lo ----
    {
      short8 wf[4][2];
#pragma unroll
      for (int ks = 0; ks < 4; ++ks) {
        wf[ks][0] = (short8)(*(const s8ma*)&wbf1[wbase0 + ks * 32]);
        wf[ks][1] = (short8)(*(const s8ma*)&wbf1[wbase1 + ks * 32]);
      }
      f32x4 acc[4][2];
#pragma unroll
      for (int rt = 0; rt < 4; ++rt) {
#pragma unroll
        for (int j = 0; j < 2; ++j) {
          float b = cb1v[(2 * wv + j) * 16 + h];
          acc[rt][j] = (f32x4){b, b, b, b};
        }
      }
#pragma unroll
      for (int ks = 0; ks < 4; ++ks) {
        const int col = ks * 32 + q * 8;
#pragma unroll
        for (int rt = 0; rt < 4; ++rt) {
          short8 ah = (short8)(*(const s8ma*)&zh[(rt * 16 + h) * 136 + col]);
          short8 al = (short8)(*(const s8ma*)&zl[(rt * 16 + h) * 136 + col]);
#pragma unroll
          for (int j = 0; j < 2; ++j) {
            acc[rt][j] = __builtin_amdgcn_mfma_f32_16x16x32_bf16(ah, wf[ks][j], acc[rt][j], 0, 0, 0);
            acc[rt][j] = __builtin_amdgcn_mfma_f32_16x16x32_bf16(al, wf[ks][j], acc[rt][j], 0, 0, 0);
          }
        }
      }
      __syncthreads();   // (4) all z2 reads done before hidden overwrite
#pragma unroll
      for (int rt = 0; rt < 4; ++rt) {
#pragma unroll
        for (int j = 0; j < 2; ++j) {
          int col = (2 * wv + j) * 16 + h;
#pragma unroll
          for (int rg = 0; rg < 4; ++rg) {
            int row = rt * 16 + q * 4 + rg;
            float v = gelu_f(acc[rt][j][rg]);
            unsigned short hi = f2bf(v);
            zh[row * 136 + col] = hi;
            zl[row * 136 + col] = f2bf(v - bf2f(hi));
          }
        }
      }
    }
    __syncthreads();   // (5) hidden visible

    // ---- P5: MFMA matmul2 (transient W frags) + per-node colsum + output ----
    {
      short8 wf[4][2];
#pragma unroll
      for (int ks = 0; ks < 4; ++ks) {
        wf[ks][0] = (short8)(*(const s8ma*)&wbf2[wbase0 + ks * 32]);
        wf[ks][1] = (short8)(*(const s8ma*)&wbf2[wbase1 + ks * 32]);
      }
      f32x4 acc[4][2];
#pragma unroll
      for (int rt = 0; rt < 4; ++rt) {
#pragma unroll
        for (int j = 0; j < 2; ++j) {
          float b = cb2v[(2 * wv + j) * 16 + h];
          acc[rt][j] = (f32x4){b, b, b, b};
        }
      }
#pragma unroll
      for (int ks = 0; ks < 4; ++ks) {
        const int col = ks * 32 + q * 8;
#pragma unroll
        for (int rt = 0; rt < 4; ++rt) {
          short8 ah = (short8)(*(const s8ma*)&zh[(rt * 16 + h) * 136 + col]);
          short8 al = (short8)(*(const s8ma*)&zl[(rt * 16 + h) * 136 + col]);
#pragma unroll
          for (int j = 0; j < 2; ++j) {
            acc[rt][j] = __builtin_amdgcn_mfma_f32_16x16x32_bf16(ah, wf[ks][j], acc[rt][j], 0, 0, 0);
            acc[rt][j] = __builtin_amdgcn_mfma_f32_16x16x32_bf16(al, wf[ks][j], acc[rt][j], 0, 0, 0);
          }
        }
      }
#pragma unroll
      for (int rt = 0; rt < 4; ++rt) {
        const int item = item4 * 4 + rt;
        const bool act = item < total_items;
        int t = 0, node = 0;
        if (act && item < 7 * NN) { t = item / NN + 1; node = item % NN; }
#pragma unroll
        for (int j = 0; j < 2; ++j) {
          float v = acc[rt][j][0] + acc[rt][j][1] + acc[rt][j][2] + acc[rt][j][3];
          v += __shfl_xor(v, 16);
          v += __shfl_xor(v, 32);
          if (q == 0 && act) {
            int col = (2 * wv + j) * 16 + h;
            out[((size_t)t * NN + node) * HH + col] = (fout[rt * 128 + col] + v) * (1.f / 16.f);
          }
        }
      }
    }
    __syncthreads();   // (6)
  }
}

// ---------------- launch ----------------

extern "C" void kernel_launch(void* const* d_in, const int* in_sizes, int n_in,
                              void* d_out, int out_size, void* d_ws, size_t ws_size,
                              hipStream_t stream) {
  const int* node_t   = (const int*)d_in[0];
  const int* edges    = (const int*)d_in[1];
  const float* emb    = (const float*)d_in[3];
  const float* convW1 = (const float*)d_in[4];
  const float* convb1 = (const float*)d_in[5];
  const float* convW2 = (const float*)d_in[6];
  const float* convb2 = (const float*)d_in[7];
  const float* tn_g   = (const float*)d_in[8];
  const float* tn_b   = (const float*)d_in[9];
  const float* tok_w1 = (const float*)d_in[10];
  const float* tok_b1 = (const float*)d_in[11];
  const float* tok_w2 = (const float*)d_in[12];
  const float* tok_b2 = (const float*)d_in[13];
  const float* cn_g   = (const float*)d_in[14];
  const float* cn_b   = (const float*)d_in[15];
  const float* ch_w1  = (const float*)d_in[16];
  const float* ch_b1  = (const float*)d_in[17];
  const float* ch_w2  = (const float*)d_in[18];
  const float* ch_b2  = (const float*)d_in[19];
  float* out = (float*)d_out;

  char* ws = (char*)d_ws;
  size_t off = 0;
  auto alloc = [&](size_t bytes) -> void* {
    void* p = ws + off;
    off += (bytes + 511) & ~(size_t)511;
    return p;
  };
  float* xw1   = (float*)alloc((size_t)NN * HH * 4);
  float* hbufs = (float*)alloc((size_t)7 * NN * HH * 4);
  float* h     = (float*)alloc((size_t)NN * HH * 4);
  float* h2    = (float*)alloc((size_t)NN * HH * 4);
  int*   cnt7  = (int*)alloc((size_t)7 * NN * 4);
  float* dinv7 = (float*)alloc((size_t)7 * NN * 4);
  int*   offs7 = (int*)alloc((size_t)7 * (NN + 1) * 4);
  int*   cursor= (int*)alloc((size_t)NN * 4);
  int*   csrc  = (int*)alloc((size_t)EE * 4);
  float* cnorm = (float*)alloc((size_t)EE * 4);
  unsigned short* wbf1 = (unsigned short*)alloc((size_t)16384 * 2);
  unsigned short* wbf2 = (unsigned short*)alloc((size_t)16384 * 2);

  gemm128_kernel<<<512, 128, 0, stream>>>(emb, convW1, xw1, NN);
  wprep_kernel<<<64, 256, 0, stream>>>(ch_w1, ch_w2, wbf1, wbf2);

  // Batched CSR prep for all 7 steps
  zero1_kernel<<<(7 * NN + 255) / 256, 256, 0, stream>>>(cnt7, 7 * NN);
  count7_kernel<<<(7 * EE + 255) / 256, 256, 0, stream>>>(edges, cnt7, 7 * EE);
  dinv_kernel<<<(7 * NN + 255) / 256, 256, 0, stream>>>(cnt7, dinv7, 7 * NN);
  scan7_kernel<<<7, 1024, 0, stream>>>(cnt7, offs7);

  for (int t = 0; t < 7; ++t) {
    const int* es = edges + (size_t)t * 2 * EE;
    const int* ed = es + EE;
    const int* offs = offs7 + (size_t)t * (NN + 1);
    const float* dinv = dinv7 + (size_t)t * NN;
    zero1_kernel<<<(NN + 255) / 256, 256, 0, stream>>>(cursor, NN);
    fillcsr_kernel<<<(EE + 255) / 256, 256, 0, stream>>>(es, ed, offs, cursor, dinv,
                                                         csrc, cnorm, EE);
    agg_kernel<<<NN, 128, 0, stream>>>(xw1, csrc, cnorm, offs, dinv, convb1, 1, h);
    gemm128_kernel<<<512, 128, 0, stream>>>(h, convW2, h2, NN);
    agg_kernel<<<NN, 128, 0, stream>>>(h2, csrc, cnorm, offs, dinv, convb2, 0,
                                       hbufs + (size_t)t * NN * HH);
    mask_kernel<<<(KK * HH + 255) / 256, 256, 0, stream>>>(
        node_t + (size_t)t * KK, hbufs + (size_t)t * NN * HH, KK);
  }

  // Fused mixer: items [0, 7*NN) = (t=1..7, node); item 7*NN = (t=0, node 0)
  const int total_items = 7 * NN + 1;
  const int nblocks = 2048;
  const int item4s = (total_items + 3) / 4;
  const int niter = (item4s + nblocks - 1) / nblocks;
  mixer18_kernel<<<nblocks, 256, 0, stream>>>(hbufs, wbf1, wbf2, tn_g, tn_b,
                                              tok_w1, tok_b1, tok_w2, tok_b2,
                                              cn_g, cn_b, ch_b1, ch_b2,
                                              out, total_items, niter);
  bcast_kernel<<<((NN * HH - 128) + 255) / 256, 256, 0, stream>>>(out, NN * HH);
}

// Round 19
// 3228.952 us; speedup vs baseline: 1.5805x; 1.5805x over previous
//
#include <hip/hip_runtime.h>
#include <hip/hip_bf16.h>
#include <cstdint>
#include <cstddef>

#define NN 20000
#define HH 128
#define MM 16
#define KK 4000
#define EE 400000

typedef __attribute__((ext_vector_type(16))) float f16v;
typedef __attribute__((ext_vector_type(8))) short short8;   // MFMA A/B operand
typedef __attribute__((ext_vector_type(4))) float f32x4;    // MFMA accumulator
typedef __attribute__((ext_vector_type(8), may_alias)) short s8ma;
typedef __attribute__((ext_vector_type(4), may_alias)) float f4ma;

__device__ __forceinline__ float gelu_f(float x) {
  return 0.5f * x * (1.0f + erff(x * 0.70710678118654752440f));
}

__device__ __forceinline__ unsigned short f2bf(float f) {
  union { float f; unsigned u; } v; v.f = f;
  unsigned u = v.u;
  unsigned r = (u + 0x7FFFu + ((u >> 16) & 1u)) >> 16;  // RNE
  return (unsigned short)r;
}
__device__ __forceinline__ float bf2f(unsigned short s) {
  union { unsigned u; float f; } v; v.u = ((unsigned)s) << 16; return v.f;
}

// ---------------- GCN helper kernels (batched across the 7 independent steps) ----------------

__global__ void zero1_kernel(int* __restrict__ a, int n) {
  int i = blockIdx.x * 256 + threadIdx.x;
  if (i < n) a[i] = 0;
}

__global__ void count7_kernel(const int* __restrict__ edges, int* __restrict__ cnt7, int n7) {
  int e = blockIdx.x * 256 + threadIdx.x;
  if (e < n7) {
    int t = e / EE, i = e - t * EE;
    int d = edges[(size_t)t * 2 * EE + EE + i];
    atomicAdd(&cnt7[t * NN + d], 1);
  }
}

__global__ void dinv_kernel(const int* __restrict__ cnt, float* __restrict__ dinv, int n) {
  int i = blockIdx.x * 256 + threadIdx.x;
  if (i < n) dinv[i] = rsqrtf((float)(cnt[i] + 1));
}

__global__ void scan7_kernel(const int* __restrict__ cnt7, int* __restrict__ offs7) {
  __shared__ int sh[1024];
  __shared__ int carry_s;
  const int b = blockIdx.x;
  const int* cnt = cnt7 + b * NN;
  int* offs = offs7 + b * (NN + 1);
  int tid = threadIdx.x;
  if (tid == 0) carry_s = 0;
  __syncthreads();
  for (int base = 0; base < NN; base += 1024) {
    int i = base + tid;
    int v = (i < NN) ? cnt[i] : 0;
    sh[tid] = v;
    __syncthreads();
    for (int off = 1; off < 1024; off <<= 1) {
      int t = (tid >= off) ? sh[tid - off] : 0;
      __syncthreads();
      sh[tid] += t;
      __syncthreads();
    }
    int carry = carry_s;
    if (i < NN) offs[i] = carry + sh[tid] - v;
    __syncthreads();
    if (tid == 1023) carry_s = carry + sh[1023];
    __syncthreads();
  }
  if (tid == 0) offs[NN] = carry_s;
}

// Batched CSR fill over nt*EE edges (edges layout [t][2][EE]).
__global__ void fillcsr7_kernel(const int* __restrict__ edges,
                                const int* __restrict__ offs7, int* __restrict__ cursor7,
                                const float* __restrict__ dinv7,
                                int* __restrict__ csrc7, float* __restrict__ cnorm7, int n7) {
  int e = blockIdx.x * 256 + threadIdx.x;
  if (e < n7) {
    int t = e / EE, i = e - t * EE;
    const int* es = edges + (size_t)t * 2 * EE;
    int s = es[i], d = es[EE + i];
    int pos = offs7[t * (NN + 1) + d] + atomicAdd(&cursor7[t * NN + d], 1);
    csrc7[(size_t)t * EE + pos] = s;
    cnorm7[(size_t)t * EE + pos] = dinv7[t * NN + s] * dinv7[t * NN + d];
  }
}

// Batched GCN aggregation: block b in [0, nt*NN); xshared=1 -> X indexed per-node
// (shared across t, e.g. xw1); else X indexed [t*NN+node]. Y indexed [b].
__global__ __launch_bounds__(128) void agg7_kernel(const float* __restrict__ X,
    const int* __restrict__ csrc7, const float* __restrict__ cnorm7,
    const int* __restrict__ offs7, const float* __restrict__ dinv7,
    const float* __restrict__ bias, int relu, float* __restrict__ Y, int xshared) {
  const int b = blockIdx.x;
  const int t = b / NN, i = b - t * NN;
  const int c = threadIdx.x;
  const int* csrc = csrc7 + (size_t)t * EE;
  const float* cnorm = cnorm7 + (size_t)t * EE;
  const int* offs = offs7 + t * (NN + 1);
  const float* dinv = dinv7 + t * NN;
  const float* Xt = xshared ? X : X + (size_t)t * NN * HH;
  float di = dinv[i];
  float acc = Xt[(size_t)i * HH + c] * di * di;
  int s0 = offs[i], e0 = offs[i + 1];
  for (int j = s0; j < e0; ++j) {
    acc += Xt[(size_t)csrc[j] * HH + c] * cnorm[j];
  }
  acc += bias[c];
  if (relu) acc = fmaxf(acc, 0.f);
  Y[(size_t)b * HH + c] = acc;
}

__global__ __launch_bounds__(128) void gemm128_kernel(const float* __restrict__ X,
    const float* __restrict__ W, float* __restrict__ Y, int nrows) {
  __shared__ float Ws[128 * 129];
  __shared__ float Xs[8 * 128];
  int tid = threadIdx.x;
  for (int idx = tid; idx < 16384; idx += 128) {
    int o = idx >> 7, k = idx & 127;
    Ws[o * 129 + k] = W[idx];
  }
  __syncthreads();
  for (int row0 = blockIdx.x * 8; row0 < nrows; row0 += gridDim.x * 8) {
    int nr = min(8, nrows - row0);
    for (int idx = tid; idx < nr * 128; idx += 128) Xs[idx] = X[(size_t)row0 * 128 + idx];
    __syncthreads();
    float acc[8] = {0, 0, 0, 0, 0, 0, 0, 0};
    for (int k = 0; k < 128; ++k) {
      float w = Ws[tid * 129 + k];
#pragma unroll
      for (int r = 0; r < 8; ++r) acc[r] += w * Xs[r * 128 + k];
    }
    for (int r = 0; r < nr; ++r) Y[(size_t)(row0 + r) * 128 + tid] = acc[r];
    __syncthreads();
  }
}

// Batched mask over nt*KK*HH.
__global__ void mask7_kernel(const int* __restrict__ node_t, float* __restrict__ hb, int n) {
  int idx = blockIdx.x * 256 + threadIdx.x;
  if (idx < n) {
    int t = idx / (KK * HH), r = idx - t * KK * HH;
    int j = r >> 7, c = r & 127;
    hb[((size_t)t * NN + node_t[t * KK + j]) * HH + c] = 0.f;
  }
}

__global__ void bcast_kernel(float* __restrict__ out, int total) {
  int idx = blockIdx.x * 256 + threadIdx.x + 128;
  if (idx < total) out[idx] = out[idx & 127];
}

// ---------------- mixer v16 (validated best: 2141us, absmax 9.77e-4) — UNCHANGED ----------------

__global__ __launch_bounds__(256) void mixer16_kernel(
    const float* __restrict__ hbufs,  // [7][NN][HH]
    const float* __restrict__ tn_g, const float* __restrict__ tn_b,
    const float* __restrict__ tok_w1, const float* __restrict__ tok_b1,
    const float* __restrict__ tok_w2, const float* __restrict__ tok_b2,
    const float* __restrict__ cn_g, const float* __restrict__ cn_b,
    const float* __restrict__ ch_w1, const float* __restrict__ ch_b1,
    const float* __restrict__ ch_w2, const float* __restrict__ ch_b2,
    float* __restrict__ out, int total_items, int niter) {
  __shared__ __align__(16) float zw[64 * 132];           // 33.8 KB f32 x tile
  __shared__ __align__(16) unsigned short zh[64 * 136];  // 17.4 KB bf16 hi
  __shared__ __align__(16) unsigned short zl[64 * 136];  // 17.4 KB bf16 lo
  __shared__ float fout[4 * 128];
  __shared__ float tg[128], tbv[128], cg[128], cbv[128], cb1v[128], cb2v[128];
  __shared__ float tw1s[256], tw2s[256], tb1s[16], tb2s[16];

  const int tid = threadIdx.x;
  const int lane = tid & 63;
  const int wv = tid >> 6;        // wave 0..3 -> og pair {2wv, 2wv+1}
  const int q = lane >> 4;
  const int h = lane & 15;

  if (tid < 128) {
    tg[tid] = tn_g[tid]; tbv[tid] = tn_b[tid];
    cg[tid] = cn_g[tid]; cbv[tid] = cn_b[tid];
    cb1v[tid] = ch_b1[tid]; cb2v[tid] = ch_b2[tid];
  }
  tw1s[tid] = tok_w1[tid];
  tw2s[tid] = tok_w2[tid];
  if (tid < 16) { tb1s[tid] = tok_b1[tid]; tb2s[tid] = tok_b2[tid]; }

  short8 wf1[4][2], wf2[4][2];
#pragma unroll
  for (int ks = 0; ks < 4; ++ks) {
#pragma unroll
    for (int j = 0; j < 2; ++j) {
      int o = (2 * wv + j) * 16 + h;
      int k0 = ks * 32 + q * 8;
      const float* s1 = ch_w1 + o * 128 + k0;
      const float* s2 = ch_w2 + o * 128 + k0;
      short8 p1, p2;
#pragma unroll
      for (int e = 0; e < 8; ++e) { p1[e] = (short)f2bf(s1[e]); p2[e] = (short)f2bf(s2[e]); }
      wf1[ks][j] = p1;
      wf2[ks][j] = p2;
    }
  }
  __syncthreads();

  const int lr = tid >> 2;
  const int lq = tid & 3;
  const int c2 = tid & 127;
  const int n0 = tid >> 7;

  for (int it = 0; it < niter; ++it) {
    const int item4 = it * gridDim.x + blockIdx.x;

    // ---- P1 ----
    {
      const int n = lr >> 4, tok = lr & 15;
      const int item = item4 * 4 + n;
      const bool act = item < total_items;
      int t = 0, node = 0;
      if (act && item < 7 * NN) { t = item / NN + 1; node = item % NN; }
      int src_t = tok - (MM - t);
      f4ma x[8];
      if (act && src_t >= 0) {
        const float* hp = hbufs + ((size_t)src_t * NN + node) * HH + lq * 32;
#pragma unroll
        for (int j = 0; j < 8; ++j) x[j] = *(const f4ma*)(hp + 4 * j);
      } else {
#pragma unroll
        for (int j = 0; j < 8; ++j) x[j] = (f4ma){0.f, 0.f, 0.f, 0.f};
      }
      float s = 0.f, ss = 0.f;
#pragma unroll
      for (int j = 0; j < 8; ++j) {
        s += x[j].x + x[j].y + x[j].z + x[j].w;
        ss += x[j].x * x[j].x + x[j].y * x[j].y + x[j].z * x[j].z + x[j].w * x[j].w;
      }
      s += __shfl_xor(s, 1); ss += __shfl_xor(ss, 1);
      s += __shfl_xor(s, 2); ss += __shfl_xor(ss, 2);
      float mu = s * (1.f / 128.f);
      float var = fmaxf(ss * (1.f / 128.f) - mu * mu, 0.f);
      float rs = rsqrtf(var + 1e-5f);
#pragma unroll
      for (int j = 0; j < 8; ++j) *(f4ma*)&zw[lr * 132 + lq * 32 + 4 * j] = x[j];
      if (lq == 0) { zw[lr * 132 + 128] = mu; zw[lr * 132 + 129] = rs; }
    }
    __syncthreads();   // (1)

    // ---- P2 ----
    {
      const int rb0 = n0 * 16 * 132, rb1 = (n0 + 2) * 16 * 132;
      const float tgc = tg[c2], tbc = tbv[c2];
      f16v a0v, a1v;
#pragma unroll
      for (int hd = 0; hd < 16; ++hd) { float b = tb1s[hd]; a0v[hd] = b; a1v[hd] = b; }
#pragma unroll
      for (int r = 0; r < 16; ++r) {
        float x0 = zw[rb0 + r * 132 + c2];
        float m0 = zw[rb0 + r * 132 + 128], q0 = zw[rb0 + r * 132 + 129];
        float x1 = zw[rb1 + r * 132 + c2];
        float m1 = zw[rb1 + r * 132 + 128], q1 = zw[rb1 + r * 132 + 129];
        float z0 = (x0 - m0) * q0 * tgc + tbc;
        float z1 = (x1 - m1) * q1 * tgc + tbc;
#pragma unroll
        for (int hd = 0; hd < 16; ++hd) {
          float w = tw1s[hd * 16 + r];
          a0v[hd] += w * z0; a1v[hd] += w * z1;
        }
      }
#pragma unroll
      for (int hd = 0; hd < 16; ++hd) { a0v[hd] = gelu_f(a0v[hd]); a1v[hd] = gelu_f(a1v[hd]); }
      float cs0 = 0.f, cs1 = 0.f;
#pragma unroll
      for (int r = 0; r < 16; ++r) {
        float o0 = tb2s[r], o1 = tb2s[r];
#pragma unroll
        for (int hd = 0; hd < 16; ++hd) {
          float w = tw2s[r * 16 + hd];
          o0 += w * a0v[hd]; o1 += w * a1v[hd];
        }
        float nx0 = zw[rb0 + r * 132 + c2] + o0;
        float nx1 = zw[rb1 + r * 132 + c2] + o1;
        cs0 += nx0; cs1 += nx1;
        zw[rb0 + r * 132 + c2] = nx0;
        zw[rb1 + r * 132 + c2] = nx1;
      }
      fout[n0 * 128 + c2] = cs0;
      fout[(n0 + 2) * 128 + c2] = cs1;
    }
    __syncthreads();   // (2)

    // ---- P3 ----
    {
      f4ma x[8];
#pragma unroll
      for (int j = 0; j < 8; ++j) x[j] = *(const f4ma*)&zw[lr * 132 + lq * 32 + 4 * j];
      float s = 0.f, ss = 0.f;
#pragma unroll
      for (int j = 0; j < 8; ++j) {
        s += x[j].x + x[j].y + x[j].z + x[j].w;
        ss += x[j].x * x[j].x + x[j].y * x[j].y + x[j].z * x[j].z + x[j].w * x[j].w;
      }
      s += __shfl_xor(s, 1); ss += __shfl_xor(ss, 1);
      s += __shfl_xor(s, 2); ss += __shfl_xor(ss, 2);
      float mu = s * (1.f / 128.f);
      float var = fmaxf(ss * (1.f / 128.f) - mu * mu, 0.f);
      float rs = rsqrtf(var + 1e-5f);
#pragma unroll
      for (int j = 0; j < 4; ++j) {
        int c0 = lq * 32 + 8 * j;
        short8 ph, pl;
#pragma unroll
        for (int e = 0; e < 8; ++e) {
          int c = c0 + e;
          float xe = (e < 4) ? ((const float*)&x[2 * j])[e] : ((const float*)&x[2 * j + 1])[e - 4];
          float zf = (xe - mu) * rs * cg[c] + cbv[c];
          unsigned short hi = f2bf(zf);
          ph[e] = (short)hi;
          pl[e] = (short)f2bf(zf - bf2f(hi));
        }
        *(s8ma*)&zh[lr * 136 + c0] = (s8ma)ph;
        *(s8ma*)&zl[lr * 136 + c0] = (s8ma)pl;
      }
    }
    __syncthreads();   // (3)

    // ---- P4 ----
    {
      f32x4 acc[4][2];
#pragma unroll
      for (int rt = 0; rt < 4; ++rt) {
#pragma unroll
        for (int j = 0; j < 2; ++j) {
          float b = cb1v[(2 * wv + j) * 16 + h];
          acc[rt][j] = (f32x4){b, b, b, b};
        }
      }
#pragma unroll
      for (int ks = 0; ks < 4; ++ks) {
        const int col = ks * 32 + q * 8;
#pragma unroll
        for (int rt = 0; rt < 4; ++rt) {
          short8 ah = (short8)(*(const s8ma*)&zh[(rt * 16 + h) * 136 + col]);
          short8 al = (short8)(*(const s8ma*)&zl[(rt * 16 + h) * 136 + col]);
#pragma unroll
          for (int j = 0; j < 2; ++j) {
            acc[rt][j] = __builtin_amdgcn_mfma_f32_16x16x32_bf16(ah, wf1[ks][j], acc[rt][j], 0, 0, 0);
            acc[rt][j] = __builtin_amdgcn_mfma_f32_16x16x32_bf16(al, wf1[ks][j], acc[rt][j], 0, 0, 0);
          }
        }
      }
      __syncthreads();   // (4)
#pragma unroll
      for (int rt = 0; rt < 4; ++rt) {
#pragma unroll
        for (int j = 0; j < 2; ++j) {
          int col = (2 * wv + j) * 16 + h;
#pragma unroll
          for (int rg = 0; rg < 4; ++rg) {
            int row = rt * 16 + q * 4 + rg;
            float v = gelu_f(acc[rt][j][rg]);
            unsigned short hi = f2bf(v);
            zh[row * 136 + col] = hi;
            zl[row * 136 + col] = f2bf(v - bf2f(hi));
          }
        }
      }
    }
    __syncthreads();   // (5)

    // ---- P5 ----
    {
      f32x4 acc[4][2];
#pragma unroll
      for (int rt = 0; rt < 4; ++rt) {
#pragma unroll
        for (int j = 0; j < 2; ++j) {
          float b = cb2v[(2 * wv + j) * 16 + h];
          acc[rt][j] = (f32x4){b, b, b, b};
        }
      }
#pragma unroll
      for (int ks = 0; ks < 4; ++ks) {
        const int col = ks * 32 + q * 8;
#pragma unroll
        for (int rt = 0; rt < 4; ++rt) {
          short8 ah = (short8)(*(const s8ma*)&zh[(rt * 16 + h) * 136 + col]);
          short8 al = (short8)(*(const s8ma*)&zl[(rt * 16 + h) * 136 + col]);
#pragma unroll
          for (int j = 0; j < 2; ++j) {
            acc[rt][j] = __builtin_amdgcn_mfma_f32_16x16x32_bf16(ah, wf2[ks][j], acc[rt][j], 0, 0, 0);
            acc[rt][j] = __builtin_amdgcn_mfma_f32_16x16x32_bf16(al, wf2[ks][j], acc[rt][j], 0, 0, 0);
          }
        }
      }
#pragma unroll
      for (int rt = 0; rt < 4; ++rt) {
        const int item = item4 * 4 + rt;
        const bool act = item < total_items;
        int t = 0, node = 0;
        if (act && item < 7 * NN) { t = item / NN + 1; node = item % NN; }
#pragma unroll
        for (int j = 0; j < 2; ++j) {
          float v = acc[rt][j][0] + acc[rt][j][1] + acc[rt][j][2] + acc[rt][j][3];
          v += __shfl_xor(v, 16);
          v += __shfl_xor(v, 32);
          if (q == 0 && act) {
            int col = (2 * wv + j) * 16 + h;
            out[((size_t)t * NN + node) * HH + col] = (fout[rt * 128 + col] + v) * (1.f / 16.f);
          }
        }
      }
    }
    __syncthreads();   // (6)
  }
}

// ---------------- launch ----------------

extern "C" void kernel_launch(void* const* d_in, const int* in_sizes, int n_in,
                              void* d_out, int out_size, void* d_ws, size_t ws_size,
                              hipStream_t stream) {
  const int* node_t   = (const int*)d_in[0];
  const int* edges    = (const int*)d_in[1];
  const float* emb    = (const float*)d_in[3];
  const float* convW1 = (const float*)d_in[4];
  const float* convb1 = (const float*)d_in[5];
  const float* convW2 = (const float*)d_in[6];
  const float* convb2 = (const float*)d_in[7];
  const float* tn_g   = (const float*)d_in[8];
  const float* tn_b   = (const float*)d_in[9];
  const float* tok_w1 = (const float*)d_in[10];
  const float* tok_b1 = (const float*)d_in[11];
  const float* tok_w2 = (const float*)d_in[12];
  const float* tok_b2 = (const float*)d_in[13];
  const float* cn_g   = (const float*)d_in[14];
  const float* cn_b   = (const float*)d_in[15];
  const float* ch_w1  = (const float*)d_in[16];
  const float* ch_b1  = (const float*)d_in[17];
  const float* ch_w2  = (const float*)d_in[18];
  const float* ch_b2  = (const float*)d_in[19];
  float* out = (float*)d_out;

  char* ws = (char*)d_ws;
  size_t off = 0;
  auto alloc = [&](size_t bytes) -> void* {
    void* p = ws + off;
    off += (bytes + 511) & ~(size_t)511;
    return p;
  };
  float* xw1   = (float*)alloc((size_t)NN * HH * 4);
  float* hbufs = (float*)alloc((size_t)7 * NN * HH * 4);
  int*   cnt7  = (int*)alloc((size_t)7 * NN * 4);
  float* dinv7 = (float*)alloc((size_t)7 * NN * 4);
  int*   offs7 = (int*)alloc((size_t)7 * (NN + 1) * 4);
  int*   cursor7 = (int*)alloc((size_t)7 * NN * 4);

  // Batched-path extra buffers need ~250 MB total; branch on ws_size (constant).
  const bool batched = ws_size >= (size_t)260 * 1024 * 1024;

  gemm128_kernel<<<512, 128, 0, stream>>>(emb, convW1, xw1, NN);

  // Degree/dinv/offset prep for all 7 steps (shared by both paths)
  zero1_kernel<<<(7 * NN + 255) / 256, 256, 0, stream>>>(cnt7, 7 * NN);
  count7_kernel<<<(7 * EE + 255) / 256, 256, 0, stream>>>(edges, cnt7, 7 * EE);
  dinv_kernel<<<(7 * NN + 255) / 256, 256, 0, stream>>>(cnt7, dinv7, 7 * NN);
  scan7_kernel<<<7, 1024, 0, stream>>>(cnt7, offs7);

  if (batched) {
    int*   csrc7  = (int*)alloc((size_t)7 * EE * 4);
    float* cnorm7 = (float*)alloc((size_t)7 * EE * 4);
    float* h7     = (float*)alloc((size_t)7 * NN * HH * 4);
    float* g7     = (float*)alloc((size_t)7 * NN * HH * 4);

    zero1_kernel<<<(7 * NN + 255) / 256, 256, 0, stream>>>(cursor7, 7 * NN);
    fillcsr7_kernel<<<(7 * EE + 255) / 256, 256, 0, stream>>>(edges, offs7, cursor7,
                                                              dinv7, csrc7, cnorm7, 7 * EE);
    agg7_kernel<<<7 * NN, 128, 0, stream>>>(xw1, csrc7, cnorm7, offs7, dinv7,
                                            convb1, 1, h7, 1);
    gemm128_kernel<<<2048, 128, 0, stream>>>(h7, convW2, g7, 7 * NN);
    agg7_kernel<<<7 * NN, 128, 0, stream>>>(g7, csrc7, cnorm7, offs7, dinv7,
                                            convb2, 0, hbufs, 0);
    mask7_kernel<<<(7 * KK * HH + 255) / 256, 256, 0, stream>>>(node_t, hbufs, 7 * KK * HH);
  } else {
    int*   csrc  = (int*)alloc((size_t)EE * 4);
    float* cnorm = (float*)alloc((size_t)EE * 4);
    float* h1    = (float*)alloc((size_t)NN * HH * 4);
    float* g1    = (float*)alloc((size_t)NN * HH * 4);
    for (int t = 0; t < 7; ++t) {
      const int* offs = offs7 + (size_t)t * (NN + 1);
      const float* dinv = dinv7 + (size_t)t * NN;
      zero1_kernel<<<(NN + 255) / 256, 256, 0, stream>>>(cursor7, NN);
      fillcsr7_kernel<<<(EE + 255) / 256, 256, 0, stream>>>(edges + (size_t)t * 2 * EE,
                                                            offs, cursor7, dinv, csrc, cnorm, EE);
      agg7_kernel<<<NN, 128, 0, stream>>>(xw1, csrc, cnorm, offs, dinv, convb1, 1, h1, 1);
      gemm128_kernel<<<512, 128, 0, stream>>>(h1, convW2, g1, NN);
      agg7_kernel<<<NN, 128, 0, stream>>>(g1, csrc, cnorm, offs, dinv, convb2, 0,
                                          hbufs + (size_t)t * NN * HH, 0);
      mask7_kernel<<<(KK * HH + 255) / 256, 256, 0, stream>>>(node_t + (size_t)t * KK,
                                                              hbufs + (size_t)t * NN * HH,
                                                              KK * HH);
    }
  }

  // Fused mixer: items [0, 7*NN) = (t=1..7, node); item 7*NN = (t=0, node 0)
  const int total_items = 7 * NN + 1;
  const int nblocks = 2048;
  const int item4s = (total_items + 3) / 4;
  const int niter = (item4s + nblocks - 1) / nblocks;
  mixer16_kernel<<<nblocks, 256, 0, stream>>>(hbufs, tn_g, tn_b, tok_w1, tok_b1, tok_w2,
                                              tok_b2, cn_g, cn_b, ch_w1, ch_b1, ch_w2,
                                              ch_b2, out, total_items, niter);
  bcast_kernel<<<((NN * HH - 128) + 255) / 256, 256, 0, stream>>>(out, NN * HH);
}